// Round 5
// baseline (192.091 us; speedup 1.0000x reference)
//
#include <hip/hip_runtime.h>

// Problem constants
#define N_PIX 4096   // 64*64 pixels
#define N_D   256    // feature dims
#define N_C   19     // classes
#define N_B   51     // bins
#define BPW   13     // bins per wave: 4 waves x 13 = 52 >= 51 (no spill: ~45 VGPR)
#define MAXCH 64     // max 64-pixel chunks (m <= 4096)
#define N_BLOCKS_MAIN (18 * 256)

// ws layout (bytes)
#define OFF_LIST   0                      // int  [19][4096]
#define OFF_COUNTS 311296                 // int  [19]
#define OFF_ACC    311424                 // float[1]
#define OFF_TICKET 311428                 // int[1]

// --- K1: bucket pixel indices by class (blocks 0..18) + feature copy (19..255)
__global__ __launch_bounds__(256) void k_pre(const float* __restrict__ feature,
                                             const int* __restrict__ label,
                                             float* __restrict__ out,
                                             int* __restrict__ list,
                                             int* __restrict__ counts,
                                             float* __restrict__ acc,
                                             int* __restrict__ ticket) {
    const int b = blockIdx.x;
    if (b < N_C) {
        // ---- bucket class b: deterministic 4-wave compaction ----
        const int c = b;
        const int w = threadIdx.x >> 6;
        const int lane = threadIdx.x & 63;
        __shared__ int wcnt[4];
        if (c == 0 && threadIdx.x == 0) { *acc = 0.f; *ticket = 0; }  // ws poisoned

        const int q0 = w * 1024;   // phase 1: count matches in my quarter
        int cnt = 0;
        for (int base = 0; base < 1024; base += 64) {
            cnt += (int)__popcll(__ballot(label[q0 + base + lane] == c));
        }
        if (lane == 0) wcnt[w] = cnt;
        __syncthreads();
        int m = 0;
#pragma unroll
        for (int i = 0; i < 4; ++i) m += (i < w) ? wcnt[i] : 0;

        for (int base = 0; base < 1024; base += 64) {  // phase 2: scatter
            const int n = q0 + base + lane;
            const bool match = (label[n] == c);
            const unsigned long long mask = __ballot(match);
            if (match) list[c * N_PIX + m + __popcll(mask & ((1ull << lane) - 1ull))] = n;
            m += (int)__popcll(mask);
        }
        if (w == 3 && lane == 0) counts[c] = m;
    } else {
        // ---- feature pass-through: out[1..] = feature[0..] ----
        const int tid = (b - N_C) * 256 + threadIdx.x;
        const int nth = (256 - N_C) * 256;
        const float4* __restrict__ src = (const float4*)feature;
        float* __restrict__ dst = out + 1;
        for (int i = tid; i < N_PIX * N_D / 4; i += nth) {
            const float4 v = src[i];
            dst[4 * i + 0] = v.x;
            dst[4 * i + 1] = v.y;
            dst[4 * i + 2] = v.z;
            dst[4 * i + 3] = v.w;
        }
    }
}

// --- K2: block = one (c,d). Pixels staged ONCE in LDS; wave w owns bins
// [w*13, w*13+13); lane owns pixel. Hot loop: 1 ds_read_b32 + 13 exp2-acc,
// zero cross-lane ops, 13 register accumulators (no spill).
// Norm factors 1/sqrt(2*pi*v) cancel after row normalization -> dropped.
__global__ __launch_bounds__(256) void k_main(const float* __restrict__ feature,
                                              const int* __restrict__ list,
                                              const int* __restrict__ counts,
                                              float* __restrict__ acc,
                                              int* __restrict__ ticket,
                                              float* __restrict__ out) {
    const int c = blockIdx.x + 1;                 // class 0 never reaches the loss
    const int d = blockIdx.y;
    const int w = threadIdx.x >> 6;
    const int lane = threadIdx.x & 63;
    const int m = counts[c];                      // block-uniform

    __shared__ float stage[MAXCH * 64];           // 16 KB pixel stage
    __shared__ float wred[8];                     // per-wave s1,s2 partials
    __shared__ float bins_s[4 * BPW];             // 52 bin sums

    if (m > 0) {                                  // uniform branch (barriers safe)
        const float* __restrict__ row = feature + d * N_PIX;  // F[:,d] contiguous
        const int* __restrict__ lst = list + c * N_PIX;
        const int nch = (m + 63) >> 6;

        // -- cooperative gather+stage (wave w: chunks w, w+4, ...) + stats --
        // pad f=-1e18: for real bins t^2 huge -> exp2(-inf)=0; for dummy bin
        // 1e18: t=-2e18 -> t^2=inf -> as*inf=-inf -> 0. Never pad +1e18.
        float s1 = 0.f, s2 = 0.f;
        for (int ch = w; ch < nch; ch += 4) {
            const int j = (ch << 6) + lane;
            const bool valid = (j < m);
            const float f = valid ? row[lst[j]] : -1e18f;
            stage[(ch << 6) + lane] = f;          // stride-1: conflict-free
            s1 += valid ? f : 0.f;
            s2 += valid ? f * f : 0.f;
        }
#pragma unroll
        for (int off = 32; off; off >>= 1) {
            s1 += __shfl_xor(s1, off);
            s2 += __shfl_xor(s2, off);
        }
        if (lane == 0) { wred[2 * w] = s1; wred[2 * w + 1] = s2; }
        __syncthreads();
        const float S1 = wred[0] + wred[2] + wred[4] + wred[6];
        const float S2 = wred[1] + wred[3] + wred[5] + wred[7];
        const float cnt = (float)m;
        const float mu = S1 / cnt;
        const float v = fmaxf(S2 / cnt - mu * mu, 1e-12f);
        const float LOG2E = 1.44269504088896340736f;
        const float as = -12.5f * LOG2E / v;      // sample: var/25 -> -0.5*25/v
        const float at = -0.5f * LOG2E / v;       // target

        // -- KDE hot loop: 13 register accumulators per lane --
        float a[BPW], binv[BPW];
#pragma unroll
        for (int i = 0; i < BPW; ++i) {
            const int bi = w * BPW + i;
            binv[i] = (bi < N_B) ? fmaf(0.2f, (float)bi, -5.0f) : 1e18f;
            a[i] = 0.f;
        }
        for (int ch = 0; ch < nch; ++ch) {
            const float f = stage[(ch << 6) + lane];
#pragma unroll
            for (int i = 0; i < BPW; ++i) {
                const float t = f - binv[i];
                a[i] += __builtin_amdgcn_exp2f(as * t * t);
            }
        }

        // -- once-per-wave reduction of 13 bins, publish to LDS --
#pragma unroll
        for (int i = 0; i < BPW; ++i) {
#pragma unroll
            for (int off = 32; off; off >>= 1) a[i] += __shfl_xor(a[i], off);
        }
        if (lane == 0) {
#pragma unroll
            for (int i = 0; i < BPW; ++i) bins_s[w * BPW + i] = a[i];
        }
        __syncthreads();

        // -- wave 0: normalize + smooth-L1 over the 51 bins (lane = bin) --
        if (w == 0) {
            const float A = (lane < N_B) ? bins_s[lane] : 0.f;
            const float bin = fmaf(0.2f, (float)lane, -5.0f);
            const float tt = bin - mu;
            const float targ = (lane < N_B) ? __builtin_amdgcn_exp2f(at * tt * tt) : 0.f;
            float ss = A, st = targ;
#pragma unroll
            for (int off = 32; off; off >>= 1) {
                ss += __shfl_xor(ss, off);
                st += __shfl_xor(st, off);
            }
            const float hist = A / fmaxf(ss, 1e-30f);
            const float tgt  = targ / fmaxf(st, 1e-30f);
            const float diff = hist - tgt;
            const float ad = fabsf(diff);
            float sl1 = (ad < 1.f) ? 0.5f * diff * diff : ad - 0.5f;
#pragma unroll
            for (int off = 32; off; off >>= 1) sl1 += __shfl_down(sl1, off);
            if (lane == 0) atomicAdd(acc, sl1);
        }
    }
    // every block (incl. m==0) takes a ticket; acc-add happens-before via fence
    if (threadIdx.x == 0) {
        __threadfence();
        const int t = atomicAdd(ticket, 1);       // device-scope
        if (t == N_BLOCKS_MAIN - 1) {             // last block finalizes
            int active = 0;
            for (int cc = 1; cc < N_C; ++cc) active += (counts[cc] > 0) ? 1 : 0;
            const float total = atomicAdd(acc, 0.0f);  // coherent read
            out[0] = total / (float)(N_D * N_B) / ((float)active + 1e-12f);
        }
    }
}

extern "C" void kernel_launch(void* const* d_in, const int* in_sizes, int n_in,
                              void* d_out, int out_size, void* d_ws, size_t ws_size,
                              hipStream_t stream) {
    const float* feature = (const float*)d_in[0];   // [1,256,64,64] fp32
    const int* label = (const int*)d_in[1];         // [1,1,64,64] int32
    float* out = (float*)d_out;                     // [0]=loss, [1..]=feature passthrough
    char* ws = (char*)d_ws;
    int* list = (int*)(ws + OFF_LIST);
    int* counts = (int*)(ws + OFF_COUNTS);
    float* acc = (float*)(ws + OFF_ACC);
    int* ticket = (int*)(ws + OFF_TICKET);

    k_pre<<<256, 256, 0, stream>>>(feature, label, out, list, counts, acc, ticket);
    dim3 grid(N_C - 1, N_D);
    k_main<<<grid, 256, 0, stream>>>(feature, list, counts, acc, ticket, out);
}

// Round 6
// 119.341 us; speedup vs baseline: 1.6096x; 1.6096x over previous
//
#include <hip/hip_runtime.h>

// Problem constants
#define N_PIX 4096   // 64*64 pixels
#define N_D   256    // feature dims
#define N_C   19     // classes
#define N_B   51     // bins
#define N_BLOCKS_MAIN (18 * 64)

// ws layout (bytes)
#define OFF_LIST   0                      // int  [19][4096]
#define OFF_COUNTS 311296                 // int  [19]
#define OFF_ACC    311424                 // float[1]
#define OFF_TICKET 311428                 // int[1]
#define OFF_GATH   524288                 // float[256][4096] = 4 MB (class-sorted feature)

// --- K1: bucket pixel indices by class (blocks 0..18) + feature copy (19..255)
__global__ __launch_bounds__(256) void k_pre(const float* __restrict__ feature,
                                             const int* __restrict__ label,
                                             float* __restrict__ out,
                                             int* __restrict__ list,
                                             int* __restrict__ counts,
                                             float* __restrict__ acc,
                                             int* __restrict__ ticket) {
    const int b = blockIdx.x;
    if (b < N_C) {
        // ---- bucket class b: deterministic 4-wave compaction ----
        const int c = b;
        const int w = threadIdx.x >> 6;
        const int lane = threadIdx.x & 63;
        __shared__ int wcnt[4];
        if (c == 0 && threadIdx.x == 0) { *acc = 0.f; *ticket = 0; }  // ws poisoned

        const int q0 = w * 1024;   // phase 1: count matches in my quarter
        int cnt = 0;
        for (int base = 0; base < 1024; base += 64) {
            cnt += (int)__popcll(__ballot(label[q0 + base + lane] == c));
        }
        if (lane == 0) wcnt[w] = cnt;
        __syncthreads();
        int m = 0;
#pragma unroll
        for (int i = 0; i < 4; ++i) m += (i < w) ? wcnt[i] : 0;

        for (int base = 0; base < 1024; base += 64) {  // phase 2: scatter
            const int n = q0 + base + lane;
            const bool match = (label[n] == c);
            const unsigned long long mask = __ballot(match);
            if (match) list[c * N_PIX + m + __popcll(mask & ((1ull << lane) - 1ull))] = n;
            m += (int)__popcll(mask);
        }
        if (w == 3 && lane == 0) counts[c] = m;
    } else {
        // ---- feature pass-through: out[1..] = feature[0..] ----
        const int tid = (b - N_C) * 256 + threadIdx.x;
        const int nth = (256 - N_C) * 256;
        const float4* __restrict__ src = (const float4*)feature;
        float* __restrict__ dst = out + 1;
        for (int i = tid; i < N_PIX * N_D / 4; i += nth) {
            const float4 v = src[i];
            dst[4 * i + 0] = v.x;
            dst[4 * i + 1] = v.y;
            dst[4 * i + 2] = v.z;
            dst[4 * i + 3] = v.w;
        }
    }
}

// --- K2: materialize class-sorted feature: gath[d][cstart[c]+j] = feature[d][list[c][j]]
// grid (256, 4): blockIdx.x = d, blockIdx.y picks classes c % 4 == y.
// Coalesced list reads + writes; 1M scattered feature reads, fully parallel.
__global__ __launch_bounds__(256) void k_gather(const float* __restrict__ feature,
                                                const int* __restrict__ list,
                                                const int* __restrict__ counts,
                                                float* __restrict__ gath) {
    const int d = blockIdx.x;
    const int tid = threadIdx.x;
    const float* __restrict__ row = feature + d * N_PIX;
    float* __restrict__ outr = gath + d * N_PIX;
    int base = 0;
    for (int c = 0; c < N_C; ++c) {
        const int mc = counts[c];
        if ((c & 3) == (int)blockIdx.y) {
            for (int j = tid; j < mc; j += 256) {
                outr[base + j] = row[list[c * N_PIX + j]];
            }
        }
        base += mc;
    }
}

// --- K3: wave = one (c,d), lane = bin. Pixels are CONTIGUOUS per (c,d) in
// gath -> hot loop reads them as wave-uniform scalar loads (SGPR broadcast,
// zero LDS / zero cross-lane / zero gather). Norm factors cancel -> dropped.
__global__ __launch_bounds__(256) void k_main(const float* __restrict__ gath,
                                              const int* __restrict__ counts,
                                              float* __restrict__ acc,
                                              int* __restrict__ ticket,
                                              float* __restrict__ out) {
    const int c = blockIdx.x + 1;                 // class 0 never reaches the loss
    const int w = threadIdx.x >> 6;
    const int d = blockIdx.y * 4 + w;
    const int lane = threadIdx.x & 63;
    const int m = counts[c];                      // block-uniform
    __shared__ float blk[4];
    float part = 0.f;
    if (m > 0) {
        int cs = 0;                               // uniform prefix sum
        for (int cc = 0; cc < c; ++cc) cs += counts[cc];
        const float* __restrict__ gr = gath + d * N_PIX + cs;

        // -- pass 1: stats. Values are wave-uniform; every lane computes the
        // same sums redundantly -> NO reduction needed. 2-way ILP chains.
        float s1a = 0.f, s1b = 0.f, s2a = 0.f, s2b = 0.f;
        int j = 0;
        for (; j + 2 <= m; j += 2) {
            const float f0 = gr[j], f1 = gr[j + 1];
            s1a += f0; s2a = fmaf(f0, f0, s2a);
            s1b += f1; s2b = fmaf(f1, f1, s2b);
        }
        if (j < m) { const float f0 = gr[j]; s1a += f0; s2a = fmaf(f0, f0, s2a); }
        const float cnt = (float)m;
        const float mu = (s1a + s1b) / cnt;
        const float v = fmaxf((s2a + s2b) / cnt - mu * mu, 1e-12f);

        const float LOG2E = 1.44269504088896340736f;
        const float as = -12.5f * LOG2E / v;      // sample kernel: var/25 -> -0.5*25/v
        const float at = -0.5f * LOG2E / v;       // target
        // lanes >= 51: bin=1e18 -> t^2 ~ 1e36 -> as*t^2 = -inf -> exp2 -> 0
        const float bin = (lane < N_B) ? fmaf(0.2f, (float)lane, -5.0f) : 1e18f;

        // -- pass 2: KDE. 8-wide batches of uniform loads; per pixel:
        // sub + mul + mul (SGPR operand) + exp2 + add. No masking (bound=m).
        float a0 = 0.f;
        int jb = 0;
        for (; jb + 8 <= m; jb += 8) {
            const float f0 = gr[jb + 0], f1 = gr[jb + 1];
            const float f2 = gr[jb + 2], f3 = gr[jb + 3];
            const float f4 = gr[jb + 4], f5 = gr[jb + 5];
            const float f6 = gr[jb + 6], f7 = gr[jb + 7];
            float t;
            t = f0 - bin; a0 += __builtin_amdgcn_exp2f(as * t * t);
            t = f1 - bin; a0 += __builtin_amdgcn_exp2f(as * t * t);
            t = f2 - bin; a0 += __builtin_amdgcn_exp2f(as * t * t);
            t = f3 - bin; a0 += __builtin_amdgcn_exp2f(as * t * t);
            t = f4 - bin; a0 += __builtin_amdgcn_exp2f(as * t * t);
            t = f5 - bin; a0 += __builtin_amdgcn_exp2f(as * t * t);
            t = f6 - bin; a0 += __builtin_amdgcn_exp2f(as * t * t);
            t = f7 - bin; a0 += __builtin_amdgcn_exp2f(as * t * t);
        }
        for (; jb < m; ++jb) {
            const float t = gr[jb] - bin;
            a0 += __builtin_amdgcn_exp2f(as * t * t);
        }

        // -- target + row normalize + smooth-L1 (one butterfly set per wave) --
        const float tt = bin - mu;
        const float targ = __builtin_amdgcn_exp2f(at * tt * tt);  // 0 for lane>=51
        float ss = a0, st = targ;
#pragma unroll
        for (int off = 32; off; off >>= 1) {
            ss += __shfl_xor(ss, off);
            st += __shfl_xor(st, off);
        }
        const float hist = a0 / fmaxf(ss, 1e-30f);
        const float tgt  = targ / fmaxf(st, 1e-30f);
        const float diff = hist - tgt;
        const float ad = fabsf(diff);
        float sl1 = (ad < 1.f) ? 0.5f * diff * diff : ad - 0.5f;
#pragma unroll
        for (int off = 32; off; off >>= 1) sl1 += __shfl_down(sl1, off);
        part = sl1;  // valid on lane 0
    }
    if (lane == 0) blk[w] = part;
    __syncthreads();  // m is block-uniform -> no divergent barrier
    if (threadIdx.x == 0) {
        atomicAdd(acc, blk[0] + blk[1] + blk[2] + blk[3]);
        __threadfence();                       // order acc-add before ticket-add
        const int t = atomicAdd(ticket, 1);    // device-scope
        if (t == N_BLOCKS_MAIN - 1) {          // last block finalizes
            int active = 0;
            for (int cc = 1; cc < N_C; ++cc) active += (counts[cc] > 0) ? 1 : 0;
            const float total = atomicAdd(acc, 0.0f);  // coherent read
            out[0] = total / (float)(N_D * N_B) / ((float)active + 1e-12f);
        }
    }
}

extern "C" void kernel_launch(void* const* d_in, const int* in_sizes, int n_in,
                              void* d_out, int out_size, void* d_ws, size_t ws_size,
                              hipStream_t stream) {
    const float* feature = (const float*)d_in[0];   // [1,256,64,64] fp32
    const int* label = (const int*)d_in[1];         // [1,1,64,64] int32
    float* out = (float*)d_out;                     // [0]=loss, [1..]=feature passthrough
    char* ws = (char*)d_ws;
    int* list = (int*)(ws + OFF_LIST);
    int* counts = (int*)(ws + OFF_COUNTS);
    float* acc = (float*)(ws + OFF_ACC);
    int* ticket = (int*)(ws + OFF_TICKET);
    float* gath = (float*)(ws + OFF_GATH);

    k_pre<<<256, 256, 0, stream>>>(feature, label, out, list, counts, acc, ticket);
    k_gather<<<dim3(256, 4), 256, 0, stream>>>(feature, list, counts, gath);
    dim3 grid(N_C - 1, N_D / 4);
    k_main<<<grid, 256, 0, stream>>>(gath, counts, acc, ticket, out);
}